// Round 3
// baseline (1211.156 us; speedup 1.0000x reference)
//
#include <hip/hip_runtime.h>

typedef __attribute__((ext_vector_type(8))) _Float16 f16x8;
typedef __attribute__((ext_vector_type(4))) _Float16 f16x4;
typedef __attribute__((ext_vector_type(4))) float f32x4;

#define DI __device__ __forceinline__

DI f32x4 mfma16(f16x8 a, f16x8 b, f32x4 c) {
    return __builtin_amdgcn_mfma_f32_16x16x32_f16(a, b, c, 0, 0, 0);
}

// Load weight fragments for 4 n-tiles x NK k-steps. wt is W^T [N][Kp] f16 row-major.
// A-operand layout: lane i=(lane&15) holds row n, k = q*8 + j (j=0..7), plus ks*32.
template <int NK>
DI void load_wf4(const _Float16* __restrict__ wt, int Kp, int nbase, int l16, int q,
                 f16x8 f[NK][4]) {
#pragma unroll
    for (int nt = 0; nt < 4; ++nt) {
        int n = nbase + nt * 16 + l16;
#pragma unroll
        for (int ks = 0; ks < NK; ++ks)
            f[ks][nt] = *(const f16x8*)(wt + n * Kp + ks * 32 + q * 8);
    }
}

// Layers 0 and 1 (both write relu'd f16 into H buffers, stride 136).
// Transposed compute: D' = W^T * X^T. B-operand: lane j=(lane&15) -> data row m,
// k = q*8+j. Output D'[n][m]: n = q*4+reg (within n-tile), m = lane&15.
template <int NK0>
DI void l01(const f16x8 (*w0f)[4], const f16x8 (*w1f)[4],
            const _Float16* __restrict__ X, int xstride,
            _Float16* __restrict__ H0, _Float16* __restrict__ H1,
            int mrow, int nh, int q) {
    const f32x4 zero = {0.f, 0.f, 0.f, 0.f};
    f32x4 acc[4];
#pragma unroll
    for (int nt = 0; nt < 4; ++nt) acc[nt] = zero;
#pragma unroll
    for (int ks = 0; ks < NK0; ++ks) {
        f16x8 x = *(const f16x8*)(X + mrow * xstride + ks * 32 + q * 8);
#pragma unroll
        for (int nt = 0; nt < 4; ++nt) acc[nt] = mfma16(w0f[ks][nt], x, acc[nt]);
    }
#pragma unroll
    for (int nt = 0; nt < 4; ++nt) {
        f16x4 h;
#pragma unroll
        for (int i = 0; i < 4; ++i) h[i] = (_Float16)fmaxf(acc[nt][i], 0.f);
        *(f16x4*)(H0 + mrow * 136 + nh * 64 + nt * 16 + q * 4) = h;
    }
    __syncthreads();
    f32x4 a1[4];
#pragma unroll
    for (int nt = 0; nt < 4; ++nt) a1[nt] = zero;
#pragma unroll
    for (int ks = 0; ks < 4; ++ks) {
        f16x8 x = *(const f16x8*)(H0 + mrow * 136 + ks * 32 + q * 8);
#pragma unroll
        for (int nt = 0; nt < 4; ++nt) a1[nt] = mfma16(w1f[ks][nt], x, a1[nt]);
    }
#pragma unroll
    for (int nt = 0; nt < 4; ++nt) {
        f16x4 h;
#pragma unroll
        for (int i = 0; i < 4; ++i) h[i] = (_Float16)fmaxf(a1[nt][i], 0.f);
        *(f16x4*)(H1 + mrow * 136 + nh * 64 + nt * 16 + q * 4) = h;
    }
    __syncthreads();
}

DI f32x4 l2(const f16x8* w2f, const _Float16* __restrict__ H1, int mrow, int q) {
    f32x4 acc = {0.f, 0.f, 0.f, 0.f};
#pragma unroll
    for (int ks = 0; ks < 4; ++ks) {
        f16x8 x = *(const f16x8*)(H1 + mrow * 136 + ks * 32 + q * 8);
        acc = mfma16(w2f[ks], x, acc);
    }
    return acc;
}

// ---------------- weight prep: fp32 [K][N] -> f16 W^T [Np][Kp] (zero padded) ----
struct WPtrs { const float* p[15]; };

__global__ void k_prep(WPtrs wp, _Float16* __restrict__ ws) {
    int b = blockIdx.x;
    const float* src; int K, N, Np, Kp, off;
    if (b == 0)       { src = wp.p[0];  K = 3;   N = 128; Np = 128; Kp = 32;  off = 0; }
    else if (b == 1)  { src = wp.p[1];  K = 128; N = 128; Np = 128; Kp = 128; off = 4096; }
    else if (b == 2)  { src = wp.p[2];  K = 128; N = 32;  Np = 32;  Kp = 128; off = 20480; }
    else if (b == 3)  { src = wp.p[3];  K = 3;   N = 128; Np = 128; Kp = 32;  off = 24576; }
    else if (b == 4)  { src = wp.p[4];  K = 128; N = 128; Np = 128; Kp = 128; off = 28672; }
    else if (b == 5)  { src = wp.p[5];  K = 128; N = 32;  Np = 32;  Kp = 128; off = 45056; }
    else if (b <= 9)  { int t = b - 6;  src = wp.p[6] + t * 12288;  K = 96;  N = 128; Np = 128; Kp = 96;  off = 49152 + t * 32768; }
    else if (b <= 13) { int t = b - 10; src = wp.p[7] + t * 16384;  K = 128; N = 128; Np = 128; Kp = 128; off = 61440 + t * 32768; }
    else if (b <= 17) { int t = b - 14; src = wp.p[8] + t * 4096;   K = 128; N = 32;  Np = 32;  Kp = 128; off = 77824 + t * 32768; }
    else if (b <= 21) { int t = b - 18; src = wp.p[9] + t * 8192;   K = 64;  N = 128; Np = 128; Kp = 64;  off = 180224 + t * 28672; }
    else if (b <= 25) { int t = b - 22; src = wp.p[10] + t * 16384; K = 128; N = 128; Np = 128; Kp = 128; off = 188416 + t * 28672; }
    else if (b <= 29) { int t = b - 26; src = wp.p[11] + t * 4096;  K = 128; N = 32;  Np = 32;  Kp = 128; off = 204800 + t * 28672; }
    else if (b == 30) { src = wp.p[12]; K = 32;  N = 128; Np = 128; Kp = 32;  off = 294912; }
    else if (b == 31) { src = wp.p[13]; K = 128; N = 128; Np = 128; Kp = 128; off = 299008; }
    else              { src = wp.p[14]; K = 128; N = 1;   Np = 16;  Kp = 128; off = 315392; }
    int total = Np * Kp;
    for (int i = threadIdx.x; i < total; i += 256) {
        int n = i / Kp, k = i - n * Kp;
        float v = (k < K && n < N) ? src[k * N + n] : 0.f;
        ws[off + i] = (_Float16)v;
    }
}

// ---------------- encoder: fp32 [M][3] -> MLP(32p->128->128->32) -> fp32 out ------
__global__ __launch_bounds__(256, 2) void k_enc(
    const float* __restrict__ in, float* __restrict__ out,
    const _Float16* __restrict__ w0t, const _Float16* __restrict__ w1t,
    const _Float16* __restrict__ w2t, int ntiles) {
    __shared__ __align__(16) _Float16 Xp[32 * 40];
    __shared__ __align__(16) _Float16 H0[32 * 136];
    __shared__ __align__(16) _Float16 H1[32 * 136];
    const int tid = threadIdx.x, wave = tid >> 6, lane = tid & 63;
    const int q = lane >> 4, l16 = lane & 15;
    const int mt = wave & 1, nh = wave >> 1;
    const int mrow = mt * 16 + l16;
    f16x8 w0f[1][4], w1f[4][4], w2f[4];
    load_wf4<1>(w0t, 32, nh * 64, l16, q, w0f);
    load_wf4<4>(w1t, 128, nh * 64, l16, q, w1f);
    {
        int n2 = nh * 16 + l16;
#pragma unroll
        for (int ks = 0; ks < 4; ++ks)
            w2f[ks] = *(const f16x8*)(w2t + n2 * 128 + ks * 32 + q * 8);
    }
    for (int tile = blockIdx.x; tile < ntiles; tile += gridDim.x) {
        int m0 = tile * 32;
        for (int c = tid; c < 1024; c += 256) {
            int r = c >> 5, cc = c & 31;
            float v = (cc < 3) ? in[(m0 + r) * 3 + cc] : 0.f;
            Xp[r * 40 + cc] = (_Float16)v;
        }
        __syncthreads();
        l01<1>(w0f, w1f, Xp, 40, H0, H1, mrow, nh, q);
        f32x4 o = l2(w2f, H1, mrow, q);
        int col = nh * 16 + q * 4;
        *(f32x4*)(out + (m0 + mrow) * 32 + col) = o;
        __syncthreads();
    }
}

// ---------------- edge update: [edge|node_s|node_r](96) -> MLP -> +res, atomic agg -
// node/edge persistent latents are fp32; f16 only at the MFMA staging boundary.
__global__ __launch_bounds__(256, 2) void k_edge(
    const float* __restrict__ node, float* __restrict__ edge,
    const int* __restrict__ gi,
    const _Float16* __restrict__ w0t, const _Float16* __restrict__ w1t,
    const _Float16* __restrict__ w2t, float* __restrict__ agg) {
    __shared__ __align__(16) _Float16 Xe[32 * 104];
    __shared__ __align__(16) _Float16 H0[32 * 136];
    __shared__ __align__(16) _Float16 H1[32 * 136];
    const int tid = threadIdx.x, wave = tid >> 6, lane = tid & 63;
    const int q = lane >> 4, l16 = lane & 15;
    const int mt = wave & 1, nh = wave >> 1;
    const int mrow = mt * 16 + l16;
    f16x8 w0f[3][4], w1f[4][4], w2f[4];
    load_wf4<3>(w0t, 96, nh * 64, l16, q, w0f);
    load_wf4<4>(w1t, 128, nh * 64, l16, q, w1f);
    {
        int n2 = nh * 16 + l16;
#pragma unroll
        for (int ks = 0; ks < 4; ++ks)
            w2f[ks] = *(const f16x8*)(w2t + n2 * 128 + ks * 32 + q * 8);
    }
    for (int tile = blockIdx.x; tile < 16000; tile += gridDim.x) {
        int e0 = tile * 32;
        // stage 96 fp32 -> f16 per row; 24 float4-chunks per row
        for (int c = tid; c < 768; c += 256) {
            int r = c / 24, s = c - r * 24;
            int e = e0 + r;
            const float* src;
            if (s < 8) src = edge + e * 32 + s * 4;
            else if (s < 16) src = node + gi[2 * e] * 32 + (s - 8) * 4;
            else src = node + gi[2 * e + 1] * 32 + (s - 16) * 4;
            f32x4 v = *(const f32x4*)src;
            f16x4 h;
#pragma unroll
            for (int i = 0; i < 4; ++i) h[i] = (_Float16)v[i];
            *(f16x4*)(Xe + r * 104 + s * 4) = h;
        }
        __syncthreads();
        l01<3>(w0f, w1f, Xe, 104, H0, H1, mrow, nh, q);
        f32x4 o = l2(w2f, H1, mrow, q);
        int e = e0 + mrow;
        int col = nh * 16 + q * 4;
        f32x4 old = *(const f32x4*)(edge + e * 32 + col);
        f32x4 nv;
#pragma unroll
        for (int i = 0; i < 4; ++i) nv[i] = o[i] + old[i];
        *(f32x4*)(edge + e * 32 + col) = nv;
        int rcv = gi[2 * e + 1];
        float* ap = agg + rcv * 32 + col;
#pragma unroll
        for (int i = 0; i < 4; ++i) unsafeAtomicAdd(ap + i, nv[i]);
        __syncthreads();
    }
}

// ---------------- node update: [node|agg](64) -> MLP -> +res -> node --------------
__global__ __launch_bounds__(256, 2) void k_node(
    float* __restrict__ node, const float* __restrict__ agg,
    const _Float16* __restrict__ w0t, const _Float16* __restrict__ w1t,
    const _Float16* __restrict__ w2t) {
    __shared__ __align__(16) _Float16 Xn[32 * 72];
    __shared__ __align__(16) _Float16 H0[32 * 136];
    __shared__ __align__(16) _Float16 H1[32 * 136];
    const int tid = threadIdx.x, wave = tid >> 6, lane = tid & 63;
    const int q = lane >> 4, l16 = lane & 15;
    const int mt = wave & 1, nh = wave >> 1;
    const int mrow = mt * 16 + l16;
    f16x8 w0f[2][4], w1f[4][4], w2f[4];
    load_wf4<2>(w0t, 64, nh * 64, l16, q, w0f);
    load_wf4<4>(w1t, 128, nh * 64, l16, q, w1f);
    {
        int n2 = nh * 16 + l16;
#pragma unroll
        for (int ks = 0; ks < 4; ++ks)
            w2f[ks] = *(const f16x8*)(w2t + n2 * 128 + ks * 32 + q * 8);
    }
    for (int tile = blockIdx.x; tile < 1000; tile += gridDim.x) {
        int n0 = tile * 32;
        // 16 float4 chunks per row: s<8 node, s>=8 agg
        for (int c = tid; c < 512; c += 256) {
            int r = c >> 4, s = c & 15;
            const float* src = (s < 8) ? (node + (n0 + r) * 32 + s * 4)
                                       : (agg + (n0 + r) * 32 + (s - 8) * 4);
            f32x4 v = *(const f32x4*)src;
            f16x4 h;
#pragma unroll
            for (int i = 0; i < 4; ++i) h[i] = (_Float16)v[i];
            *(f16x4*)(Xn + r * 72 + s * 4) = h;
        }
        __syncthreads();
        l01<2>(w0f, w1f, Xn, 72, H0, H1, mrow, nh, q);
        f32x4 o = l2(w2f, H1, mrow, q);
        int col = nh * 16 + q * 4;
        f32x4 old = *(const f32x4*)(node + (n0 + mrow) * 32 + col);
        f32x4 nv;
#pragma unroll
        for (int i = 0; i < 4; ++i) nv[i] = o[i] + old[i];
        *(f32x4*)(node + (n0 + mrow) * 32 + col) = nv;
        __syncthreads();
    }
}

// ---------------- decoder: node(32) -> MLP(32->128->128->1) -> fp32 out ----------
__global__ __launch_bounds__(256, 2) void k_dec(
    const float* __restrict__ node,
    const _Float16* __restrict__ w0t, const _Float16* __restrict__ w1t,
    const _Float16* __restrict__ w2t, float* __restrict__ out) {
    __shared__ __align__(16) _Float16 Xd[32 * 40];
    __shared__ __align__(16) _Float16 H0[32 * 136];
    __shared__ __align__(16) _Float16 H1[32 * 136];
    const int tid = threadIdx.x, wave = tid >> 6, lane = tid & 63;
    const int q = lane >> 4, l16 = lane & 15;
    const int mt = wave & 1, nh = wave >> 1;
    const int mrow = mt * 16 + l16;
    f16x8 w0f[1][4], w1f[4][4], w2f[4];
    load_wf4<1>(w0t, 32, nh * 64, l16, q, w0f);
    load_wf4<4>(w1t, 128, nh * 64, l16, q, w1f);
    {
        int n2 = l16;  // padded W2^T is [16][128]; all waves load tile 0
#pragma unroll
        for (int ks = 0; ks < 4; ++ks)
            w2f[ks] = *(const f16x8*)(w2t + n2 * 128 + ks * 32 + q * 8);
    }
    for (int tile = blockIdx.x; tile < 1000; tile += gridDim.x) {
        int m0 = tile * 32;
        for (int c = tid; c < 256; c += 256) {
            int r = c >> 3, s = c & 7;
            f32x4 v = *(const f32x4*)(node + (m0 + r) * 32 + s * 4);
            f16x4 h;
#pragma unroll
            for (int i = 0; i < 4; ++i) h[i] = (_Float16)v[i];
            *(f16x4*)(Xd + r * 40 + s * 4) = h;
        }
        __syncthreads();
        l01<1>(w0f, w1f, Xd, 40, H0, H1, mrow, nh, q);
        if (nh == 0) {
            f32x4 o = l2(w2f, H1, mrow, q);
            if (q == 0) out[m0 + mrow] = o[0];  // feature n=0 lives in reg 0 of quad 0
        }
        __syncthreads();
    }
}

extern "C" void kernel_launch(void* const* d_in, const int* in_sizes, int n_in,
                              void* d_out, int out_size, void* d_ws, size_t ws_size,
                              hipStream_t stream) {
    const float* input_node = (const float*)d_in[0];
    const float* input_edge = (const float*)d_in[1];
    const int* gi = (const int*)d_in[2];

    _Float16* ws = (_Float16*)d_ws;
    // ws layout (bytes):
    //   weights f16:         [0, 634,880)
    //   node fp32 32000x32:  [655,360, 4,751,360)
    //   edge fp32 512000x32: [4,751,360, 70,287,360)
    //   agg fp32 32000x32:   [70,287,360, 74,383,360)
    float* node = (float*)((char*)d_ws + 655360);
    float* edge = (float*)((char*)d_ws + 4751360);
    float* agg  = (float*)((char*)d_ws + 70287360);

    WPtrs wp;
    for (int i = 0; i < 15; ++i) wp.p[i] = (const float*)d_in[3 + i];

    k_prep<<<33, 256, 0, stream>>>(wp, ws);

    k_enc<<<512, 256, 0, stream>>>(input_node, node, ws + 0, ws + 4096, ws + 20480, 1000);
    k_enc<<<512, 256, 0, stream>>>(input_edge, edge, ws + 24576, ws + 28672, ws + 45056, 16000);

    for (int t = 0; t < 4; ++t) {
        hipMemsetAsync(agg, 0, 32000 * 32 * sizeof(float), stream);
        k_edge<<<512, 256, 0, stream>>>(node, edge, gi,
                                        ws + 49152 + t * 32768,
                                        ws + 61440 + t * 32768,
                                        ws + 77824 + t * 32768, agg);
        k_node<<<512, 256, 0, stream>>>(node, agg,
                                        ws + 180224 + t * 28672,
                                        ws + 188416 + t * 28672,
                                        ws + 204800 + t * 28672);
    }
    k_dec<<<512, 256, 0, stream>>>(node, ws + 294912, ws + 299008, ws + 315392,
                                   (float*)d_out);
}